// Round 1
// baseline (8052.437 us; speedup 1.0000x reference)
//
#include <hip/hip_runtime.h>
#include <math.h>

static constexpr int kN0  = 100000;
static constexpr int kN1  = 20000;
static constexpr int kN2  = 4000;
static constexpr int kDeg = 10;
static constexpr int kD   = 512;
static constexpr int kED  = 256;
static constexpr int kCD  = 300;
static constexpr int kFF  = 2048;

// ---------------------------------------------------------------------------
// Fused node_h: h = (emb@ee_w^T + ee_b) + LN(leaky(content@proj_w^T + proj_b))*g+b
//               h /= max(||h||,1e-5)
// Block: 16 rows x 512 cols, 256 threads, per-thread 4x8 micro-tile (x2 accums).
// ---------------------------------------------------------------------------
__global__ __launch_bounds__(256) void node_h_kernel(
    const int* __restrict__ nid,
    const float* __restrict__ content,
    const float* __restrict__ node_emb_w,
    const float* __restrict__ ee_w, const float* __restrict__ ee_b,
    const float* __restrict__ proj_w, const float* __restrict__ proj_b,
    const float* __restrict__ proj_g, const float* __restrict__ proj_beta,
    float* __restrict__ hout, int ldh, int n)
{
    __shared__ __align__(16) float smem[560 * 16 + 8 * 512]; // 13056 floats
    float* At = smem;            // [560][16]  A tile, transposed (k-major)
    float* Bs = smem + 560 * 16; // [8][512]   B tile for current k-chunk
    float* S2 = smem;            // [16][520]  (aliases At after K loop)
    float* pp = smem + 16 * 520; // [16][64]   row-norm partials
    __shared__ float meanv[16], rstdv[16], invn[16];

    const int t    = threadIdx.x;
    const int tx   = t & 63;   // col group: cols tx*8 .. tx*8+7
    const int ty   = t >> 6;   // row group: rows ty*4 .. ty*4+3
    const int row0 = blockIdx.x * 16;

    // ---- stage gathered A rows into LDS (transposed) --------------------
    for (int r = 0; r < 16; ++r) {
        int row = row0 + r; if (row >= n) row = n - 1;
        const float* emb = node_emb_w + (size_t)(nid[row] + 1) * kED;
        const float* con = content + (size_t)row * kCD;
        for (int k = t; k < 560; k += 256) {
            float v = 0.f;
            if (k < 256)      v = emb[k];
            else if (k < 556) v = con[k - 256];
            At[k * 16 + r] = v;
        }
    }

    float acc1[4][8], acc2[4][8];
    #pragma unroll
    for (int r = 0; r < 4; ++r)
        #pragma unroll
        for (int c = 0; c < 8; ++c) { acc1[r][c] = 0.f; acc2[r][c] = 0.f; }

    for (int k0 = 0; k0 < 560; k0 += 8) {
        // load B chunk: Bs[kk][j]
        #pragma unroll
        for (int jj = 0; jj < 2; ++jj) {
            int j = t * 2 + jj;
            #pragma unroll
            for (int kk = 0; kk < 8; ++kk) {
                int k = k0 + kk;
                float v = 0.f;
                if (k < 256)      v = ee_w[(size_t)j * kED + k];
                else if (k < 556) v = proj_w[(size_t)j * kCD + (k - 256)];
                Bs[kk * 512 + j] = v;
            }
        }
        __syncthreads();
        float (*acc)[8] = (k0 < 256) ? acc1 : acc2;
        #pragma unroll
        for (int kk = 0; kk < 8; ++kk) {
            float4 av = *(const float4*)&At[(k0 + kk) * 16 + ty * 4];
            float a[4] = {av.x, av.y, av.z, av.w};
            float4 b0 = *(const float4*)&Bs[kk * 512 + tx * 8];
            float4 b1 = *(const float4*)&Bs[kk * 512 + tx * 8 + 4];
            float bv[8] = {b0.x, b0.y, b0.z, b0.w, b1.x, b1.y, b1.z, b1.w};
            #pragma unroll
            for (int r = 0; r < 4; ++r)
                #pragma unroll
                for (int c = 0; c < 8; ++c)
                    acc[r][c] = fmaf(a[r], bv[c], acc[r][c]);
        }
        __syncthreads();
    }

    // ---- epilogue: bias, leaky, LN over 512, add, row-normalize ---------
    const int colbase = tx * 8;
    #pragma unroll
    for (int r = 0; r < 4; ++r) {
        int lr = ty * 4 + r;
        #pragma unroll
        for (int c = 0; c < 8; ++c) {
            int col = colbase + c;
            acc1[r][c] += ee_b[col];
            float v = acc2[r][c] + proj_b[col];
            v = (v >= 0.f) ? v : 0.1f * v;
            acc2[r][c] = v;
            S2[lr * 520 + col] = v;
        }
    }
    __syncthreads();
    {   // LN stats: group g (16 threads) reduces row g
        int g = t >> 4, l = t & 15;
        float s = 0.f, sq = 0.f;
        for (int c = l; c < 512; c += 16) {
            float v = S2[g * 520 + c];
            s += v; sq = fmaf(v, v, sq);
        }
        #pragma unroll
        for (int off = 8; off > 0; off >>= 1) {
            s  += __shfl_down(s, off, 16);
            sq += __shfl_down(sq, off, 16);
        }
        if (l == 0) {
            float m   = s * (1.f / 512.f);
            float var = sq * (1.f / 512.f) - m * m;
            meanv[g] = m;
            rstdv[g] = rsqrtf(var + 1e-5f);
        }
    }
    __syncthreads();
    #pragma unroll
    for (int r = 0; r < 4; ++r) {
        int lr = ty * 4 + r;
        float m = meanv[lr], rs = rstdv[lr];
        float psq = 0.f;
        #pragma unroll
        for (int c = 0; c < 8; ++c) {
            int col = colbase + c;
            float cv = (acc2[r][c] - m) * rs * proj_g[col] + proj_beta[col];
            float h  = acc1[r][c] + cv;
            acc1[r][c] = h;
            psq = fmaf(h, h, psq);
        }
        pp[lr * 64 + tx] = psq;
    }
    __syncthreads();
    {
        int g = t >> 4, l = t & 15;
        float s = pp[g * 64 + l] + pp[g * 64 + l + 16] +
                  pp[g * 64 + l + 32] + pp[g * 64 + l + 48];
        #pragma unroll
        for (int off = 8; off > 0; off >>= 1) s += __shfl_down(s, off, 16);
        if (l == 0) invn[g] = 1.f / fmaxf(sqrtf(s), 1e-5f);
    }
    __syncthreads();
    #pragma unroll
    for (int r = 0; r < 4; ++r) {
        int row = row0 + ty * 4 + r;
        if (row < n) {
            float iv = invn[ty * 4 + r];
            float4 o0 = make_float4(acc1[r][0] * iv, acc1[r][1] * iv,
                                    acc1[r][2] * iv, acc1[r][3] * iv);
            float4 o1 = make_float4(acc1[r][4] * iv, acc1[r][5] * iv,
                                    acc1[r][6] * iv, acc1[r][7] * iv);
            float* dst = hout + (size_t)row * ldh + colbase;
            *(float4*)dst       = o0;
            *(float4*)(dst + 4) = o1;
        }
    }
}

// ---------------------------------------------------------------------------
// Generic GEMM: C[:, nb*512 .. +512] = A(MxK, lda) @ W(nb rows slice)^T + bias
// EPI: 0=plain  1=gelu(exact)  2=residual+LayerNorm (requires N-tile == full 512)
// ---------------------------------------------------------------------------
__device__ inline float gelu_exact(float x) {
    return 0.5f * x * (1.f + erff(x * 0.70710678118654752f));
}

template<int EPI>
__global__ __launch_bounds__(256) void gemm16_kernel(
    const float* __restrict__ A, int lda,
    const float* __restrict__ W, const float* __restrict__ bias,
    float* __restrict__ C, int ldc,
    const float* __restrict__ resid,
    const float* __restrict__ lng, const float* __restrict__ lnb,
    int M, int K)
{
    __shared__ __align__(16) float smem[9344];
    float* As = smem;          // [8][16]
    float* Bs = smem + 128;    // [8][512]
    float* S  = smem;          // [16][520]  (aliases, post K-loop)
    float* pp = smem + 8320;   // [16][64]   (unused except scratch)
    (void)pp;
    __shared__ float meanv[16], rstdv[16];

    const int t    = threadIdx.x;
    const int tx   = t & 63;
    const int ty   = t >> 6;
    const int row0 = blockIdx.x * 16;
    const int nb   = blockIdx.y;
    const float* Wb = W + (size_t)nb * 512 * K;

    float acc[4][8];
    #pragma unroll
    for (int r = 0; r < 4; ++r)
        #pragma unroll
        for (int c = 0; c < 8; ++c) acc[r][c] = 0.f;

    for (int k0 = 0; k0 < K; k0 += 8) {
        if (t < 128) {
            int r = t >> 3, kk = t & 7;
            int row = row0 + r;
            As[kk * 16 + r] = (row < M) ? A[(size_t)row * lda + k0 + kk] : 0.f;
        }
        #pragma unroll
        for (int jj = 0; jj < 2; ++jj) {
            int j = t * 2 + jj;
            const float* wr = Wb + (size_t)j * K + k0;
            float4 w0 = *(const float4*)wr;
            float4 w1 = *(const float4*)(wr + 4);
            Bs[0 * 512 + j] = w0.x; Bs[1 * 512 + j] = w0.y;
            Bs[2 * 512 + j] = w0.z; Bs[3 * 512 + j] = w0.w;
            Bs[4 * 512 + j] = w1.x; Bs[5 * 512 + j] = w1.y;
            Bs[6 * 512 + j] = w1.z; Bs[7 * 512 + j] = w1.w;
        }
        __syncthreads();
        #pragma unroll
        for (int kk = 0; kk < 8; ++kk) {
            float4 av = *(const float4*)&As[kk * 16 + ty * 4];
            float a[4] = {av.x, av.y, av.z, av.w};
            float4 b0 = *(const float4*)&Bs[kk * 512 + tx * 8];
            float4 b1 = *(const float4*)&Bs[kk * 512 + tx * 8 + 4];
            float bv[8] = {b0.x, b0.y, b0.z, b0.w, b1.x, b1.y, b1.z, b1.w};
            #pragma unroll
            for (int r = 0; r < 4; ++r)
                #pragma unroll
                for (int c = 0; c < 8; ++c)
                    acc[r][c] = fmaf(a[r], bv[c], acc[r][c]);
        }
        __syncthreads();
    }

    const int colbase = tx * 8;
    #pragma unroll
    for (int r = 0; r < 4; ++r)
        #pragma unroll
        for (int c = 0; c < 8; ++c)
            acc[r][c] += bias[nb * 512 + colbase + c];

    if constexpr (EPI == 0 || EPI == 1) {
        #pragma unroll
        for (int r = 0; r < 4; ++r) {
            int row = row0 + ty * 4 + r;
            if (row < M) {
                float v[8];
                #pragma unroll
                for (int c = 0; c < 8; ++c)
                    v[c] = (EPI == 1) ? gelu_exact(acc[r][c]) : acc[r][c];
                float* dst = C + (size_t)row * ldc + nb * 512 + colbase;
                *(float4*)dst       = make_float4(v[0], v[1], v[2], v[3]);
                *(float4*)(dst + 4) = make_float4(v[4], v[5], v[6], v[7]);
            }
        }
    } else {
        // residual + LayerNorm over the full 512-wide row (nb == 0, ldc == 512)
        #pragma unroll
        for (int r = 0; r < 4; ++r) {
            int lr = ty * 4 + r;
            int row = row0 + lr; if (row >= M) row = M - 1;
            #pragma unroll
            for (int c = 0; c < 8; ++c) {
                float h = resid[(size_t)row * 512 + colbase + c] + acc[r][c];
                acc[r][c] = h;
                S[lr * 520 + colbase + c] = h;
            }
        }
        __syncthreads();
        {
            int g = t >> 4, l = t & 15;
            float s = 0.f, sq = 0.f;
            for (int c = l; c < 512; c += 16) {
                float v = S[g * 520 + c];
                s += v; sq = fmaf(v, v, sq);
            }
            #pragma unroll
            for (int off = 8; off > 0; off >>= 1) {
                s  += __shfl_down(s, off, 16);
                sq += __shfl_down(sq, off, 16);
            }
            if (l == 0) {
                float m   = s * (1.f / 512.f);
                float var = sq * (1.f / 512.f) - m * m;
                meanv[g] = m;
                rstdv[g] = rsqrtf(var + 1e-5f);
            }
        }
        __syncthreads();
        #pragma unroll
        for (int r = 0; r < 4; ++r) {
            int lr = ty * 4 + r;
            int row = row0 + lr;
            if (row < M) {
                float m = meanv[lr], rs = rstdv[lr];
                float v[8];
                #pragma unroll
                for (int c = 0; c < 8; ++c) {
                    int col = colbase + c;
                    v[c] = (acc[r][c] - m) * rs * lng[col] + lnb[col];
                }
                float* dst = C + (size_t)row * 512 + colbase;
                *(float4*)dst       = make_float4(v[0], v[1], v[2], v[3]);
                *(float4*)(dst + 4) = make_float4(v[4], v[5], v[6], v[7]);
            }
        }
    }
}

// ---------------------------------------------------------------------------
// agg_mean over 10 contiguous edges + concat-normalize (builds h1cat rows)
// ---------------------------------------------------------------------------
__device__ inline float block_sum256(float v, float* red4) {
    #pragma unroll
    for (int off = 32; off > 0; off >>= 1) v += __shfl_down(v, off);
    if ((threadIdx.x & 63) == 0) red4[threadIdx.x >> 6] = v;
    __syncthreads();
    return red4[0] + red4[1] + red4[2] + red4[3];
}

__global__ __launch_bounds__(256) void agg_norm1_kernel(
    const float* __restrict__ h0, const int* __restrict__ esrc,
    float* __restrict__ h1cat)
{
    __shared__ int idx[kDeg];
    __shared__ float red4[4];
    int i = blockIdx.x, t = threadIdx.x;
    if (t < kDeg) idx[t] = esrc[i * kDeg + t];
    __syncthreads();
    float s0 = 0.f, s1 = 0.f;
    for (int e = 0; e < kDeg; ++e) {
        const float* hr = h0 + (size_t)idx[e] * 512;
        s0 += hr[t]; s1 += hr[t + 256];
    }
    s0 *= 0.1f; s1 *= 0.1f;
    size_t base = (size_t)i * 1024;
    float o0 = h1cat[base + 512 + t];
    float o1 = h1cat[base + 768 + t];
    float tot = block_sum256(s0 * s0 + s1 * s1 + o0 * o0 + o1 * o1, red4);
    float inv = 1.f / fmaxf(sqrtf(tot), 1e-5f);
    h1cat[base + t]       = s0 * inv;
    h1cat[base + 256 + t] = s1 * inv;
    h1cat[base + 512 + t] = o0 * inv;
    h1cat[base + 768 + t] = o1 * inv;
}

__global__ __launch_bounds__(256) void agg2_kernel(
    const float* __restrict__ h1cat, const int* __restrict__ esrc,
    float* __restrict__ m2)
{
    __shared__ int idx[kDeg];
    int i = blockIdx.x, t = threadIdx.x;
    if (t < kDeg) idx[t] = esrc[i * kDeg + t];
    __syncthreads();
    float s0 = 0.f, s1 = 0.f, s2 = 0.f, s3 = 0.f;
    for (int e = 0; e < kDeg; ++e) {
        const float* hr = h1cat + (size_t)idx[e] * 1024;
        s0 += hr[t]; s1 += hr[t + 256]; s2 += hr[t + 512]; s3 += hr[t + 768];
    }
    size_t base = (size_t)i * 1024;
    m2[base + t]       = s0 * 0.1f;
    m2[base + 256 + t] = s1 * 0.1f;
    m2[base + 512 + t] = s2 * 0.1f;
    m2[base + 768 + t] = s3 * 0.1f;
}

// ---------------------------------------------------------------------------
// Cross-attention combine: 2 heads x 256 dims, 2 memory slots, softmax over 2
// ---------------------------------------------------------------------------
__global__ __launch_bounds__(256) void attn_combine_kernel(
    const float* __restrict__ Q,
    const float* __restrict__ K0, const float* __restrict__ K1,
    const float* __restrict__ V0, const float* __restrict__ V1,
    float* __restrict__ O)
{
    __shared__ float red[4][4];
    __shared__ float a[4];
    int i = blockIdx.x, t = threadIdx.x;
    size_t base = (size_t)i * 512;
    float q0 = Q[base + t], q1 = Q[base + t + 256];
    float p00 = q0 * K0[base + t];
    float p01 = q0 * K1[base + t];
    float p10 = q1 * K0[base + t + 256];
    float p11 = q1 * K1[base + t + 256];
    #pragma unroll
    for (int off = 32; off > 0; off >>= 1) {
        p00 += __shfl_down(p00, off);
        p01 += __shfl_down(p01, off);
        p10 += __shfl_down(p10, off);
        p11 += __shfl_down(p11, off);
    }
    int w = t >> 6;
    if ((t & 63) == 0) { red[w][0] = p00; red[w][1] = p01; red[w][2] = p10; red[w][3] = p11; }
    __syncthreads();
    if (t == 0) {
        float s00 = (red[0][0] + red[1][0] + red[2][0] + red[3][0]) * 0.0625f;
        float s01 = (red[0][1] + red[1][1] + red[2][1] + red[3][1]) * 0.0625f;
        float s10 = (red[0][2] + red[1][2] + red[2][2] + red[3][2]) * 0.0625f;
        float s11 = (red[0][3] + red[1][3] + red[2][3] + red[3][3]) * 0.0625f;
        float m0 = fmaxf(s00, s01);
        float e0 = expf(s00 - m0), e1 = expf(s01 - m0);
        float d0 = e0 + e1;
        a[0] = e0 / d0; a[1] = e1 / d0;
        float m1 = fmaxf(s10, s11);
        float f0 = expf(s10 - m1), f1 = expf(s11 - m1);
        float d1 = f0 + f1;
        a[2] = f0 / d1; a[3] = f1 / d1;
    }
    __syncthreads();
    O[base + t]       = a[0] * V0[base + t]       + a[1] * V1[base + t];
    O[base + t + 256] = a[2] * V0[base + t + 256] + a[3] * V1[base + t + 256];
}

__global__ __launch_bounds__(256) void final_norm_kernel(
    const float* __restrict__ tgt, float* __restrict__ out)
{
    __shared__ float red4[4];
    int i = blockIdx.x, t = threadIdx.x;
    size_t base = (size_t)i * 512;
    float v0 = tgt[base + t], v1 = tgt[base + t + 256];
    float tot = block_sum256(v0 * v0 + v1 * v1, red4);
    float inv = 1.f / fmaxf(sqrtf(tot), 1e-5f);
    out[base + t]       = v0 * inv;
    out[base + t + 256] = v1 * inv;
}

// ---------------------------------------------------------------------------
extern "C" void kernel_launch(void* const* d_in, const int* in_sizes, int n_in,
                              void* d_out, int out_size, void* d_ws, size_t ws_size,
                              hipStream_t stream)
{
    (void)in_sizes; (void)n_in; (void)out_size; (void)ws_size;
    const int*   nid0       = (const int*)d_in[0];
    const int*   nid1       = (const int*)d_in[1];
    const int*   nid2       = (const int*)d_in[2];
    const int*   esrc0      = (const int*)d_in[3];
    const int*   esrc1      = (const int*)d_in[5];
    const float* content0   = (const float*)d_in[7];
    const float* content1   = (const float*)d_in[8];
    const float* content2   = (const float*)d_in[9];
    const float* node_emb_w = (const float*)d_in[10];
    const float* ee_w       = (const float*)d_in[11];
    const float* ee_b       = (const float*)d_in[12];
    const float* proj_w     = (const float*)d_in[13];
    const float* proj_b     = (const float*)d_in[14];
    const float* proj_g     = (const float*)d_in[15];
    const float* proj_beta  = (const float*)d_in[16];
    const float* sa_in_w    = (const float*)d_in[17];
    const float* sa_in_b    = (const float*)d_in[18];
    const float* sa_out_w   = (const float*)d_in[19];
    const float* sa_out_b   = (const float*)d_in[20];
    const float* ca_in_w    = (const float*)d_in[21];
    const float* ca_in_b    = (const float*)d_in[22];
    const float* ca_out_w   = (const float*)d_in[23];
    const float* ca_out_b   = (const float*)d_in[24];
    const float* lin1_w     = (const float*)d_in[25];
    const float* lin1_b     = (const float*)d_in[26];
    const float* lin2_w     = (const float*)d_in[27];
    const float* lin2_b     = (const float*)d_in[28];
    const float* n1_g       = (const float*)d_in[29];
    const float* n1_b       = (const float*)d_in[30];
    const float* n2_g       = (const float*)d_in[31];
    const float* n2_b       = (const float*)d_in[32];
    const float* n3_g       = (const float*)d_in[33];
    const float* n3_b       = (const float*)d_in[34];

    float* ws = (float*)d_ws;
    size_t off = 0;
    float* h0    = ws + off; off += (size_t)kN0 * 512;
    float* h1cat = ws + off; off += (size_t)kN1 * 1024;
    float* m2    = ws + off; off += (size_t)kN2 * 1024;
    float* tgt   = ws + off; off += (size_t)kN2 * 512;
    float* Qb    = ws + off; off += (size_t)kN2 * 512;
    float* K0b   = ws + off; off += (size_t)kN2 * 512;
    float* K1b   = ws + off; off += (size_t)kN2 * 512;
    float* V0b   = ws + off; off += (size_t)kN2 * 512;
    float* V1b   = ws + off; off += (size_t)kN2 * 512;
    float* Ob    = ws + off; off += (size_t)kN2 * 512;
    float* ffh   = ws + off; off += (size_t)kN2 * 2048;

    dim3 blk(256);

    node_h_kernel<<<dim3((kN0 + 15) / 16), blk, 0, stream>>>(
        nid0, content0, node_emb_w, ee_w, ee_b, proj_w, proj_b, proj_g, proj_beta,
        h0, 512, kN0);
    node_h_kernel<<<dim3((kN1 + 15) / 16), blk, 0, stream>>>(
        nid1, content1, node_emb_w, ee_w, ee_b, proj_w, proj_b, proj_g, proj_beta,
        h1cat + 512, 1024, kN1);
    node_h_kernel<<<dim3((kN2 + 15) / 16), blk, 0, stream>>>(
        nid2, content2, node_emb_w, ee_w, ee_b, proj_w, proj_b, proj_g, proj_beta,
        tgt, 512, kN2);

    agg_norm1_kernel<<<dim3(kN1), blk, 0, stream>>>(h0, esrc0, h1cat);
    agg2_kernel<<<dim3(kN2), blk, 0, stream>>>(h1cat, esrc1, m2);

    const int M = kN2;
    dim3 g512(M / 16, 1), g2048(M / 16, 4);
    for (int l = 0; l < 2; ++l) {
        const float* sa_w = sa_in_w + (size_t)l * 3 * kD * kD;
        const float* sa_b = sa_in_b + (size_t)l * 3 * kD;
        const float* saow = sa_out_w + (size_t)l * kD * kD;
        const float* saob = sa_out_b + (size_t)l * kD;
        const float* ca_w = ca_in_w + (size_t)l * 3 * kD * kD;
        const float* ca_b = ca_in_b + (size_t)l * 3 * kD;
        const float* caow = ca_out_w + (size_t)l * kD * kD;
        const float* caob = ca_out_b + (size_t)l * kD;
        const float* l1w = lin1_w + (size_t)l * kFF * kD;
        const float* l1b = lin1_b + (size_t)l * kFF;
        const float* l2w = lin2_w + (size_t)l * kD * kFF;
        const float* l2b = lin2_b + (size_t)l * kFF / 4; // (kD) -- see below
        l2b = lin2_b + (size_t)l * kD;

        // self-attention, seq len 1 => softmax==1 => o = v
        gemm16_kernel<0><<<g512, blk, 0, stream>>>(
            tgt, 512, sa_w + (size_t)2 * kD * kD, sa_b + 2 * kD,
            Qb, 512, nullptr, nullptr, nullptr, M, 512);
        gemm16_kernel<2><<<g512, blk, 0, stream>>>(
            Qb, 512, saow, saob, tgt, 512, tgt, n1_g + l * kD, n1_b + l * kD, M, 512);

        // cross-attention
        gemm16_kernel<0><<<g512, blk, 0, stream>>>(
            tgt, 512, ca_w, ca_b, Qb, 512, nullptr, nullptr, nullptr, M, 512);
        gemm16_kernel<0><<<g512, blk, 0, stream>>>(
            m2, 1024, ca_w + (size_t)kD * kD, ca_b + kD,
            K0b, 512, nullptr, nullptr, nullptr, M, 512);
        gemm16_kernel<0><<<g512, blk, 0, stream>>>(
            m2 + 512, 1024, ca_w + (size_t)kD * kD, ca_b + kD,
            K1b, 512, nullptr, nullptr, nullptr, M, 512);
        gemm16_kernel<0><<<g512, blk, 0, stream>>>(
            m2, 1024, ca_w + (size_t)2 * kD * kD, ca_b + 2 * kD,
            V0b, 512, nullptr, nullptr, nullptr, M, 512);
        gemm16_kernel<0><<<g512, blk, 0, stream>>>(
            m2 + 512, 1024, ca_w + (size_t)2 * kD * kD, ca_b + 2 * kD,
            V1b, 512, nullptr, nullptr, nullptr, M, 512);
        attn_combine_kernel<<<dim3(M), blk, 0, stream>>>(Qb, K0b, K1b, V0b, V1b, Ob);
        gemm16_kernel<2><<<g512, blk, 0, stream>>>(
            Ob, 512, caow, caob, tgt, 512, tgt, n2_g + l * kD, n2_b + l * kD, M, 512);

        // feed-forward
        gemm16_kernel<1><<<g2048, blk, 0, stream>>>(
            tgt, 512, l1w, l1b, ffh, 2048, nullptr, nullptr, nullptr, M, 512);
        gemm16_kernel<2><<<g512, blk, 0, stream>>>(
            ffh, 2048, l2w, l2b, tgt, 512, tgt, n3_g + l * kD, n3_b + l * kD, M, 2048);
    }

    final_norm_kernel<<<dim3(kN2), blk, 0, stream>>>(tgt, (float*)d_out);
}

// Round 2
// 3340.377 us; speedup vs baseline: 2.4106x; 2.4106x over previous
//
#include <hip/hip_runtime.h>
#include <math.h>

static constexpr int kN0  = 100000;
static constexpr int kN1  = 20000;
static constexpr int kN2  = 4000;
static constexpr int kDeg = 10;
static constexpr int kD   = 512;
static constexpr int kFF  = 2048;
static constexpr int kKP   = 576;  // padded K (256 emb + 300 content + 20 zero)
static constexpr int kRows = 48;   // rows per node_h block
static constexpr int kLdA  = 584;  // LDS row stride in bf16 elems (+8 pad)

using short8  = __attribute__((ext_vector_type(8))) short;
using floatx4 = __attribute__((ext_vector_type(4))) float;

__device__ inline unsigned short f2bf(float f) {
    union { float f; unsigned u; } v; v.f = f;
    unsigned r = v.u + 0x7FFFu + ((v.u >> 16) & 1u);  // RNE
    return (unsigned short)(r >> 16);
}

// ---------------------------------------------------------------------------
// Pack node_h weights into bf16 b-frag order for mfma_f32_16x16x32_bf16.
// Bp[kc][coltile][lane][j] = W[coltile*16 + (lane&15)][kc*32 + (lane>>4)*8 + j]
// where W[n][k] = k<256 ? ee_w[n][k] : (k<556 ? proj_w[n][k-256] : 0)
// 576 tiles * 64 lanes * 8 bf16 = 294912 ushorts = 589824 B.
// ---------------------------------------------------------------------------
__global__ __launch_bounds__(256) void pack_node_w_kernel(
    const float* __restrict__ ee_w, const float* __restrict__ proj_w,
    ushort* __restrict__ Bp)
{
    int tid  = blockIdx.x * 256 + threadIdx.x;   // 0 .. 36863
    int lane = tid & 63;
    int tile = tid >> 6;                          // kc*32 + ct, 0..575
    int n     = (tile & 31) * 16 + (lane & 15);
    int kbase = (tile >> 5) * 32 + (lane >> 4) * 8;
    ushort v[8];
    #pragma unroll
    for (int j = 0; j < 8; ++j) {
        int k = kbase + j;
        float f = 0.f;
        if (k < 256)      f = ee_w[(size_t)n * 256 + k];
        else if (k < 556) f = proj_w[(size_t)n * 300 + (k - 256)];
        v[j] = f2bf(f);
    }
    uint4 u;
    u.x = (unsigned)v[0] | ((unsigned)v[1] << 16);
    u.y = (unsigned)v[2] | ((unsigned)v[3] << 16);
    u.z = (unsigned)v[4] | ((unsigned)v[5] << 16);
    u.w = (unsigned)v[6] | ((unsigned)v[7] << 16);
    *(uint4*)(Bp + (size_t)tid * 8) = u;
}

// ---------------------------------------------------------------------------
// MFMA node_h: 48 rows x 512 cols per block, 512 threads (8 waves).
// Wave w covers cols [w*64, w*64+64) as 4 col-tiles; 3 row-tiles of 16.
// Two accumulator sets: kc 0..7 -> emb path (nh), kc 8..17 -> content path (c).
// Epilogue: bias, leaky, LN(512), add, row-normalize — fused.
// ---------------------------------------------------------------------------
__global__ __launch_bounds__(512, 2) void node_h_mfma(
    const int* __restrict__ nid,
    const float* __restrict__ content,
    const float* __restrict__ node_emb_w,
    const ushort* __restrict__ Bp,
    const float* __restrict__ ee_b, const float* __restrict__ proj_b,
    const float* __restrict__ proj_g, const float* __restrict__ proj_beta,
    float* __restrict__ hout, int ldh, int n)
{
    __shared__ __align__(16) ushort As[kRows * kLdA];      // 56064 B
    __shared__ float redS[8][kRows], redQ[8][kRows];       // 3072 B
    __shared__ float meanv[kRows], rstdv[kRows], rowinv[kRows];

    const int t    = threadIdx.x;
    const int lane = t & 63;
    const int wv   = t >> 6;          // 0..7
    const int quad = lane >> 4;
    const int l15  = lane & 15;
    const int row0 = blockIdx.x * kRows;

    // ---- stage A (48 rows x 576 k) fp32 -> bf16 into LDS ----------------
    // 144 float4 slots per row: [0,64) emb, [64,139) content, [139,144) zero
    for (int it = 0; it < 14; ++it) {
        int flat = it * 512 + t;
        if (flat < kRows * 144) {
            int r  = flat / 144;
            int k4 = flat - r * 144;
            int row = row0 + r; if (row >= n) row = n - 1;
            float4 f = make_float4(0.f, 0.f, 0.f, 0.f);
            if (k4 < 64)
                f = *(const float4*)(node_emb_w + ((size_t)(nid[row] + 1)) * 256 + k4 * 4);
            else if (k4 < 139)
                f = *(const float4*)(content + (size_t)row * 300 + (k4 - 64) * 4);
            ushort4 o = make_ushort4(f2bf(f.x), f2bf(f.y), f2bf(f.z), f2bf(f.w));
            *(ushort4*)(As + (size_t)r * kLdA + k4 * 4) = o;
        }
    }
    __syncthreads();

    floatx4 accN[3][4] = {};   // emb path  (k 0..255)
    floatx4 accC[3][4] = {};   // content path (k 256..575)

    const short8* BpV = (const short8*)Bp;

    #pragma unroll
    for (int kc = 0; kc < 8; ++kc) {   // emb chunks
        const short8* bp = BpV + (size_t)(kc * 32 + wv * 4) * 64 + lane;
        short8 b0 = bp[0], b1 = bp[64], b2 = bp[128], b3 = bp[192];
        short8 a[3];
        #pragma unroll
        for (int rt = 0; rt < 3; ++rt)
            a[rt] = *(const short8*)(As + (size_t)(rt * 16 + l15) * kLdA + kc * 32 + quad * 8);
        #pragma unroll
        for (int rt = 0; rt < 3; ++rt) {
            accN[rt][0] = __builtin_amdgcn_mfma_f32_16x16x32_bf16(a[rt], b0, accN[rt][0], 0, 0, 0);
            accN[rt][1] = __builtin_amdgcn_mfma_f32_16x16x32_bf16(a[rt], b1, accN[rt][1], 0, 0, 0);
            accN[rt][2] = __builtin_amdgcn_mfma_f32_16x16x32_bf16(a[rt], b2, accN[rt][2], 0, 0, 0);
            accN[rt][3] = __builtin_amdgcn_mfma_f32_16x16x32_bf16(a[rt], b3, accN[rt][3], 0, 0, 0);
        }
    }
    #pragma unroll
    for (int kc = 8; kc < 18; ++kc) {  // content chunks
        const short8* bp = BpV + (size_t)(kc * 32 + wv * 4) * 64 + lane;
        short8 b0 = bp[0], b1 = bp[64], b2 = bp[128], b3 = bp[192];
        short8 a[3];
        #pragma unroll
        for (int rt = 0; rt < 3; ++rt)
            a[rt] = *(const short8*)(As + (size_t)(rt * 16 + l15) * kLdA + kc * 32 + quad * 8);
        #pragma unroll
        for (int rt = 0; rt < 3; ++rt) {
            accC[rt][0] = __builtin_amdgcn_mfma_f32_16x16x32_bf16(a[rt], b0, accC[rt][0], 0, 0, 0);
            accC[rt][1] = __builtin_amdgcn_mfma_f32_16x16x32_bf16(a[rt], b1, accC[rt][1], 0, 0, 0);
            accC[rt][2] = __builtin_amdgcn_mfma_f32_16x16x32_bf16(a[rt], b2, accC[rt][2], 0, 0, 0);
            accC[rt][3] = __builtin_amdgcn_mfma_f32_16x16x32_bf16(a[rt], b3, accC[rt][3], 0, 0, 0);
        }
    }

    // ---- epilogue -------------------------------------------------------
    const int colbase = wv * 64 + l15;
    float pb[4], pg[4], pbt[4], eb[4];
    #pragma unroll
    for (int ct = 0; ct < 4; ++ct) {
        int c = colbase + ct * 16;
        pb[ct]  = proj_b[c];
        pg[ct]  = proj_g[c];
        pbt[ct] = proj_beta[c];
        eb[ct]  = ee_b[c];
    }

    // pass 1: bias + leaky, per-row partial sums for LN
    float s12[12], q12[12];
    #pragma unroll
    for (int rt = 0; rt < 3; ++rt) {
        #pragma unroll
        for (int i = 0; i < 4; ++i) {
            float s = 0.f, q = 0.f;
            #pragma unroll
            for (int ct = 0; ct < 4; ++ct) {
                float c = accC[rt][ct][i] + pb[ct];
                c = (c >= 0.f) ? c : 0.1f * c;
                accC[rt][ct][i] = c;
                s += c; q = fmaf(c, c, q);
            }
            s12[rt * 4 + i] = s; q12[rt * 4 + i] = q;
        }
    }
    #pragma unroll
    for (int idx = 0; idx < 12; ++idx) {
        #pragma unroll
        for (int m = 1; m < 16; m <<= 1) {
            s12[idx] += __shfl_xor(s12[idx], m);
            q12[idx] += __shfl_xor(q12[idx], m);
        }
    }
    if (l15 == 0) {
        #pragma unroll
        for (int rt = 0; rt < 3; ++rt)
            #pragma unroll
            for (int i = 0; i < 4; ++i) {
                int rl = rt * 16 + quad * 4 + i;
                redS[wv][rl] = s12[rt * 4 + i];
                redQ[wv][rl] = q12[rt * 4 + i];
            }
    }
    __syncthreads();
    if (t < kRows) {
        float s = 0.f, q = 0.f;
        #pragma unroll
        for (int w = 0; w < 8; ++w) { s += redS[w][t]; q += redQ[w][t]; }
        float m   = s * (1.f / 512.f);
        float var = q * (1.f / 512.f) - m * m;
        meanv[t] = m;
        rstdv[t] = rsqrtf(var + 1e-5f);
    }
    __syncthreads();

    // pass 2: LN transform + add emb path, per-row sumsq for normalize
    #pragma unroll
    for (int rt = 0; rt < 3; ++rt) {
        #pragma unroll
        for (int i = 0; i < 4; ++i) {
            int rl = rt * 16 + quad * 4 + i;
            float m = meanv[rl], rs = rstdv[rl];
            float psq = 0.f;
            #pragma unroll
            for (int ct = 0; ct < 4; ++ct) {
                float cn = (accC[rt][ct][i] - m) * rs * pg[ct] + pbt[ct];
                float h  = accN[rt][ct][i] + eb[ct] + cn;
                accN[rt][ct][i] = h;
                psq = fmaf(h, h, psq);
            }
            q12[rt * 4 + i] = psq;
        }
    }
    #pragma unroll
    for (int idx = 0; idx < 12; ++idx)
        #pragma unroll
        for (int m = 1; m < 16; m <<= 1)
            q12[idx] += __shfl_xor(q12[idx], m);
    if (l15 == 0) {
        #pragma unroll
        for (int rt = 0; rt < 3; ++rt)
            #pragma unroll
            for (int i = 0; i < 4; ++i)
                redS[wv][rt * 16 + quad * 4 + i] = q12[rt * 4 + i];
    }
    __syncthreads();
    if (t < kRows) {
        float s = 0.f;
        #pragma unroll
        for (int w = 0; w < 8; ++w) s += redS[w][t];
        rowinv[t] = 1.f / fmaxf(sqrtf(s), 1e-5f);
    }
    __syncthreads();

    #pragma unroll
    for (int rt = 0; rt < 3; ++rt) {
        #pragma unroll
        for (int i = 0; i < 4; ++i) {
            int rl = rt * 16 + quad * 4 + i;
            int grow = row0 + rl;
            if (grow < n) {
                float inv = rowinv[rl];
                float* dst = hout + (size_t)grow * ldh + colbase;
                #pragma unroll
                for (int ct = 0; ct < 4; ++ct)
                    dst[ct * 16] = accN[rt][ct][i] * inv;
            }
        }
    }
}

// ---------------------------------------------------------------------------
// Generic fp32 GEMM (unchanged from R1): C = A @ W^T + bias, 16-row tiles.
// EPI: 0=plain  1=gelu(exact)  2=residual+LayerNorm
// ---------------------------------------------------------------------------
__device__ inline float gelu_exact(float x) {
    return 0.5f * x * (1.f + erff(x * 0.70710678118654752f));
}

template<int EPI>
__global__ __launch_bounds__(256) void gemm16_kernel(
    const float* __restrict__ A, int lda,
    const float* __restrict__ W, const float* __restrict__ bias,
    float* __restrict__ C, int ldc,
    const float* __restrict__ resid,
    const float* __restrict__ lng, const float* __restrict__ lnb,
    int M, int K)
{
    __shared__ __align__(16) float smem[9344];
    float* As = smem;          // [8][16]
    float* Bs = smem + 128;    // [8][512]
    float* S  = smem;          // [16][520]  (aliases, post K-loop)
    __shared__ float meanv[16], rstdv[16];

    const int t    = threadIdx.x;
    const int tx   = t & 63;
    const int ty   = t >> 6;
    const int row0 = blockIdx.x * 16;
    const int nb   = blockIdx.y;
    const float* Wb = W + (size_t)nb * 512 * K;

    float acc[4][8];
    #pragma unroll
    for (int r = 0; r < 4; ++r)
        #pragma unroll
        for (int c = 0; c < 8; ++c) acc[r][c] = 0.f;

    for (int k0 = 0; k0 < K; k0 += 8) {
        if (t < 128) {
            int r = t >> 3, kk = t & 7;
            int row = row0 + r;
            As[kk * 16 + r] = (row < M) ? A[(size_t)row * lda + k0 + kk] : 0.f;
        }
        #pragma unroll
        for (int jj = 0; jj < 2; ++jj) {
            int j = t * 2 + jj;
            const float* wr = Wb + (size_t)j * K + k0;
            float4 w0 = *(const float4*)wr;
            float4 w1 = *(const float4*)(wr + 4);
            Bs[0 * 512 + j] = w0.x; Bs[1 * 512 + j] = w0.y;
            Bs[2 * 512 + j] = w0.z; Bs[3 * 512 + j] = w0.w;
            Bs[4 * 512 + j] = w1.x; Bs[5 * 512 + j] = w1.y;
            Bs[6 * 512 + j] = w1.z; Bs[7 * 512 + j] = w1.w;
        }
        __syncthreads();
        #pragma unroll
        for (int kk = 0; kk < 8; ++kk) {
            float4 av = *(const float4*)&As[kk * 16 + ty * 4];
            float a[4] = {av.x, av.y, av.z, av.w};
            float4 b0 = *(const float4*)&Bs[kk * 512 + tx * 8];
            float4 b1 = *(const float4*)&Bs[kk * 512 + tx * 8 + 4];
            float bv[8] = {b0.x, b0.y, b0.z, b0.w, b1.x, b1.y, b1.z, b1.w};
            #pragma unroll
            for (int r = 0; r < 4; ++r)
                #pragma unroll
                for (int c = 0; c < 8; ++c)
                    acc[r][c] = fmaf(a[r], bv[c], acc[r][c]);
        }
        __syncthreads();
    }

    const int colbase = tx * 8;
    #pragma unroll
    for (int r = 0; r < 4; ++r)
        #pragma unroll
        for (int c = 0; c < 8; ++c)
            acc[r][c] += bias[nb * 512 + colbase + c];

    if constexpr (EPI == 0 || EPI == 1) {
        #pragma unroll
        for (int r = 0; r < 4; ++r) {
            int row = row0 + ty * 4 + r;
            if (row < M) {
                float v[8];
                #pragma unroll
                for (int c = 0; c < 8; ++c)
                    v[c] = (EPI == 1) ? gelu_exact(acc[r][c]) : acc[r][c];
                float* dst = C + (size_t)row * ldc + nb * 512 + colbase;
                *(float4*)dst       = make_float4(v[0], v[1], v[2], v[3]);
                *(float4*)(dst + 4) = make_float4(v[4], v[5], v[6], v[7]);
            }
        }
    } else {
        #pragma unroll
        for (int r = 0; r < 4; ++r) {
            int lr = ty * 4 + r;
            int row = row0 + lr; if (row >= M) row = M - 1;
            #pragma unroll
            for (int c = 0; c < 8; ++c) {
                float h = resid[(size_t)row * 512 + colbase + c] + acc[r][c];
                acc[r][c] = h;
                S[lr * 520 + colbase + c] = h;
            }
        }
        __syncthreads();
        {
            int g = t >> 4, l = t & 15;
            float s = 0.f, sq = 0.f;
            for (int c = l; c < 512; c += 16) {
                float v = S[g * 520 + c];
                s += v; sq = fmaf(v, v, sq);
            }
            #pragma unroll
            for (int off = 8; off > 0; off >>= 1) {
                s  += __shfl_down(s, off, 16);
                sq += __shfl_down(sq, off, 16);
            }
            if (l == 0) {
                float m   = s * (1.f / 512.f);
                float var = sq * (1.f / 512.f) - m * m;
                meanv[g] = m;
                rstdv[g] = rsqrtf(var + 1e-5f);
            }
        }
        __syncthreads();
        #pragma unroll
        for (int r = 0; r < 4; ++r) {
            int lr = ty * 4 + r;
            int row = row0 + lr;
            if (row < M) {
                float m = meanv[lr], rs = rstdv[lr];
                float v[8];
                #pragma unroll
                for (int c = 0; c < 8; ++c) {
                    int col = colbase + c;
                    v[c] = (acc[r][c] - m) * rs * lng[col] + lnb[col];
                }
                float* dst = C + (size_t)row * 512 + colbase;
                *(float4*)dst       = make_float4(v[0], v[1], v[2], v[3]);
                *(float4*)(dst + 4) = make_float4(v[4], v[5], v[6], v[7]);
            }
        }
    }
}

// ---------------------------------------------------------------------------
__device__ inline float block_sum256(float v, float* red4) {
    #pragma unroll
    for (int off = 32; off > 0; off >>= 1) v += __shfl_down(v, off);
    if ((threadIdx.x & 63) == 0) red4[threadIdx.x >> 6] = v;
    __syncthreads();
    return red4[0] + red4[1] + red4[2] + red4[3];
}

__global__ __launch_bounds__(256) void agg_norm1_kernel(
    const float* __restrict__ h0, const int* __restrict__ esrc,
    float* __restrict__ h1cat)
{
    __shared__ int idx[kDeg];
    __shared__ float red4[4];
    int i = blockIdx.x, t = threadIdx.x;
    if (t < kDeg) idx[t] = esrc[i * kDeg + t];
    __syncthreads();
    float s0 = 0.f, s1 = 0.f;
    for (int e = 0; e < kDeg; ++e) {
        const float* hr = h0 + (size_t)idx[e] * 512;
        s0 += hr[t]; s1 += hr[t + 256];
    }
    s0 *= 0.1f; s1 *= 0.1f;
    size_t base = (size_t)i * 1024;
    float o0 = h1cat[base + 512 + t];
    float o1 = h1cat[base + 768 + t];
    float tot = block_sum256(s0 * s0 + s1 * s1 + o0 * o0 + o1 * o1, red4);
    float inv = 1.f / fmaxf(sqrtf(tot), 1e-5f);
    h1cat[base + t]       = s0 * inv;
    h1cat[base + 256 + t] = s1 * inv;
    h1cat[base + 512 + t] = o0 * inv;
    h1cat[base + 768 + t] = o1 * inv;
}

__global__ __launch_bounds__(256) void agg2_kernel(
    const float* __restrict__ h1cat, const int* __restrict__ esrc,
    float* __restrict__ m2)
{
    __shared__ int idx[kDeg];
    int i = blockIdx.x, t = threadIdx.x;
    if (t < kDeg) idx[t] = esrc[i * kDeg + t];
    __syncthreads();
    float s0 = 0.f, s1 = 0.f, s2 = 0.f, s3 = 0.f;
    for (int e = 0; e < kDeg; ++e) {
        const float* hr = h1cat + (size_t)idx[e] * 1024;
        s0 += hr[t]; s1 += hr[t + 256]; s2 += hr[t + 512]; s3 += hr[t + 768];
    }
    size_t base = (size_t)i * 1024;
    m2[base + t]       = s0 * 0.1f;
    m2[base + 256 + t] = s1 * 0.1f;
    m2[base + 512 + t] = s2 * 0.1f;
    m2[base + 768 + t] = s3 * 0.1f;
}

__global__ __launch_bounds__(256) void attn_combine_kernel(
    const float* __restrict__ Q,
    const float* __restrict__ K0, const float* __restrict__ K1,
    const float* __restrict__ V0, const float* __restrict__ V1,
    float* __restrict__ O)
{
    __shared__ float red[4][4];
    __shared__ float a[4];
    int i = blockIdx.x, t = threadIdx.x;
    size_t base = (size_t)i * 512;
    float q0 = Q[base + t], q1 = Q[base + t + 256];
    float p00 = q0 * K0[base + t];
    float p01 = q0 * K1[base + t];
    float p10 = q1 * K0[base + t + 256];
    float p11 = q1 * K1[base + t + 256];
    #pragma unroll
    for (int off = 32; off > 0; off >>= 1) {
        p00 += __shfl_down(p00, off);
        p01 += __shfl_down(p01, off);
        p10 += __shfl_down(p10, off);
        p11 += __shfl_down(p11, off);
    }
    int w = t >> 6;
    if ((t & 63) == 0) { red[w][0] = p00; red[w][1] = p01; red[w][2] = p10; red[w][3] = p11; }
    __syncthreads();
    if (t == 0) {
        float s00 = (red[0][0] + red[1][0] + red[2][0] + red[3][0]) * 0.0625f;
        float s01 = (red[0][1] + red[1][1] + red[2][1] + red[3][1]) * 0.0625f;
        float s10 = (red[0][2] + red[1][2] + red[2][2] + red[3][2]) * 0.0625f;
        float s11 = (red[0][3] + red[1][3] + red[2][3] + red[3][3]) * 0.0625f;
        float m0 = fmaxf(s00, s01);
        float e0 = expf(s00 - m0), e1 = expf(s01 - m0);
        float d0 = e0 + e1;
        a[0] = e0 / d0; a[1] = e1 / d0;
        float m1 = fmaxf(s10, s11);
        float f0 = expf(s10 - m1), f1 = expf(s11 - m1);
        float d1 = f0 + f1;
        a[2] = f0 / d1; a[3] = f1 / d1;
    }
    __syncthreads();
    O[base + t]       = a[0] * V0[base + t]       + a[1] * V1[base + t];
    O[base + t + 256] = a[2] * V0[base + t + 256] + a[3] * V1[base + t + 256];
}

__global__ __launch_bounds__(256) void final_norm_kernel(
    const float* __restrict__ tgt, float* __restrict__ out)
{
    __shared__ float red4[4];
    int i = blockIdx.x, t = threadIdx.x;
    size_t base = (size_t)i * 512;
    float v0 = tgt[base + t], v1 = tgt[base + t + 256];
    float tot = block_sum256(v0 * v0 + v1 * v1, red4);
    float inv = 1.f / fmaxf(sqrtf(tot), 1e-5f);
    out[base + t]       = v0 * inv;
    out[base + t + 256] = v1 * inv;
}

// ---------------------------------------------------------------------------
extern "C" void kernel_launch(void* const* d_in, const int* in_sizes, int n_in,
                              void* d_out, int out_size, void* d_ws, size_t ws_size,
                              hipStream_t stream)
{
    (void)in_sizes; (void)n_in; (void)out_size; (void)ws_size;
    const int*   nid0       = (const int*)d_in[0];
    const int*   nid1       = (const int*)d_in[1];
    const int*   nid2       = (const int*)d_in[2];
    const int*   esrc0      = (const int*)d_in[3];
    const int*   esrc1      = (const int*)d_in[5];
    const float* content0   = (const float*)d_in[7];
    const float* content1   = (const float*)d_in[8];
    const float* content2   = (const float*)d_in[9];
    const float* node_emb_w = (const float*)d_in[10];
    const float* ee_w       = (const float*)d_in[11];
    const float* ee_b       = (const float*)d_in[12];
    const float* proj_w     = (const float*)d_in[13];
    const float* proj_b     = (const float*)d_in[14];
    const float* proj_g     = (const float*)d_in[15];
    const float* proj_beta  = (const float*)d_in[16];
    const float* sa_in_w    = (const float*)d_in[17];
    const float* sa_in_b    = (const float*)d_in[18];
    const float* sa_out_w   = (const float*)d_in[19];
    const float* sa_out_b   = (const float*)d_in[20];
    const float* ca_in_w    = (const float*)d_in[21];
    const float* ca_in_b    = (const float*)d_in[22];
    const float* ca_out_w   = (const float*)d_in[23];
    const float* ca_out_b   = (const float*)d_in[24];
    const float* lin1_w     = (const float*)d_in[25];
    const float* lin1_b     = (const float*)d_in[26];
    const float* lin2_w     = (const float*)d_in[27];
    const float* lin2_b     = (const float*)d_in[28];
    const float* n1_g       = (const float*)d_in[29];
    const float* n1_b       = (const float*)d_in[30];
    const float* n2_g       = (const float*)d_in[31];
    const float* n2_b       = (const float*)d_in[32];
    const float* n3_g       = (const float*)d_in[33];
    const float* n3_b       = (const float*)d_in[34];

    float* ws = (float*)d_ws;
    size_t off = 0;
    float* h0    = ws + off; off += (size_t)kN0 * 512;
    float* h1cat = ws + off; off += (size_t)kN1 * 1024;
    float* m2    = ws + off; off += (size_t)kN2 * 1024;
    float* tgt   = ws + off; off += (size_t)kN2 * 512;
    float* Qb    = ws + off; off += (size_t)kN2 * 512;
    float* K0b   = ws + off; off += (size_t)kN2 * 512;
    float* K1b   = ws + off; off += (size_t)kN2 * 512;
    float* V0b   = ws + off; off += (size_t)kN2 * 512;
    float* V1b   = ws + off; off += (size_t)kN2 * 512;
    float* Ob    = ws + off; off += (size_t)kN2 * 512;
    float* ffh   = ws + off; off += (size_t)kN2 * 2048;
    ushort* Bp   = (ushort*)(ws + off); off += 147456;  // 576*64*8 bf16

    dim3 blk(256);

    pack_node_w_kernel<<<dim3(144), blk, 0, stream>>>(ee_w, proj_w, Bp);

    node_h_mfma<<<dim3((kN0 + kRows - 1) / kRows), dim3(512), 0, stream>>>(
        nid0, content0, node_emb_w, Bp, ee_b, proj_b, proj_g, proj_beta,
        h0, 512, kN0);
    node_h_mfma<<<dim3((kN1 + kRows - 1) / kRows), dim3(512), 0, stream>>>(
        nid1, content1, node_emb_w, Bp, ee_b, proj_b, proj_g, proj_beta,
        h1cat + 512, 1024, kN1);
    node_h_mfma<<<dim3((kN2 + kRows - 1) / kRows), dim3(512), 0, stream>>>(
        nid2, content2, node_emb_w, Bp, ee_b, proj_b, proj_g, proj_beta,
        tgt, 512, kN2);

    agg_norm1_kernel<<<dim3(kN1), blk, 0, stream>>>(h0, esrc0, h1cat);
    agg2_kernel<<<dim3(kN2), blk, 0, stream>>>(h1cat, esrc1, m2);

    const int M = kN2;
    dim3 g512(M / 16, 1), g2048(M / 16, 4);
    for (int l = 0; l < 2; ++l) {
        const float* sa_w = sa_in_w + (size_t)l * 3 * kD * kD;
        const float* sa_b = sa_in_b + (size_t)l * 3 * kD;
        const float* saow = sa_out_w + (size_t)l * kD * kD;
        const float* saob = sa_out_b + (size_t)l * kD;
        const float* ca_w = ca_in_w + (size_t)l * 3 * kD * kD;
        const float* ca_b = ca_in_b + (size_t)l * 3 * kD;
        const float* caow = ca_out_w + (size_t)l * kD * kD;
        const float* caob = ca_out_b + (size_t)l * kD;
        const float* l1w = lin1_w + (size_t)l * kFF * kD;
        const float* l1b = lin1_b + (size_t)l * kFF;
        const float* l2w = lin2_w + (size_t)l * kD * kFF;
        const float* l2b = lin2_b + (size_t)l * kD;

        // self-attention, seq len 1 => softmax==1 => o = v
        gemm16_kernel<0><<<g512, blk, 0, stream>>>(
            tgt, 512, sa_w + (size_t)2 * kD * kD, sa_b + 2 * kD,
            Qb, 512, nullptr, nullptr, nullptr, M, 512);
        gemm16_kernel<2><<<g512, blk, 0, stream>>>(
            Qb, 512, saow, saob, tgt, 512, tgt, n1_g + l * kD, n1_b + l * kD, M, 512);

        // cross-attention
        gemm16_kernel<0><<<g512, blk, 0, stream>>>(
            tgt, 512, ca_w, ca_b, Qb, 512, nullptr, nullptr, nullptr, M, 512);
        gemm16_kernel<0><<<g512, blk, 0, stream>>>(
            m2, 1024, ca_w + (size_t)kD * kD, ca_b + kD,
            K0b, 512, nullptr, nullptr, nullptr, M, 512);
        gemm16_kernel<0><<<g512, blk, 0, stream>>>(
            m2 + 512, 1024, ca_w + (size_t)kD * kD, ca_b + kD,
            K1b, 512, nullptr, nullptr, nullptr, M, 512);
        gemm16_kernel<0><<<g512, blk, 0, stream>>>(
            m2, 1024, ca_w + (size_t)2 * kD * kD, ca_b + 2 * kD,
            V0b, 512, nullptr, nullptr, nullptr, M, 512);
        gemm16_kernel<0><<<g512, blk, 0, stream>>>(
            m2 + 512, 1024, ca_w + (size_t)2 * kD * kD, ca_b + 2 * kD,
            V1b, 512, nullptr, nullptr, nullptr, M, 512);
        attn_combine_kernel<<<dim3(M), blk, 0, stream>>>(Qb, K0b, K1b, V0b, V1b, Ob);
        gemm16_kernel<2><<<g512, blk, 0, stream>>>(
            Ob, 512, caow, caob, tgt, 512, tgt, n2_g + l * kD, n2_b + l * kD, M, 512);

        // feed-forward
        gemm16_kernel<1><<<g2048, blk, 0, stream>>>(
            tgt, 512, l1w, l1b, ffh, 2048, nullptr, nullptr, nullptr, M, 512);
        gemm16_kernel<2><<<g512, blk, 0, stream>>>(
            ffh, 2048, l2w, l2b, tgt, 512, tgt, n3_g + l * kD, n3_b + l * kD, M, 2048);
    }

    final_norm_kernel<<<dim3(kN2), blk, 0, stream>>>(tgt, (float*)d_out);
}

// Round 3
// 1266.709 us; speedup vs baseline: 6.3570x; 2.6371x over previous
//
#include <hip/hip_runtime.h>
#include <math.h>

static constexpr int kN0  = 100000;
static constexpr int kN1  = 20000;
static constexpr int kN2  = 4000;
static constexpr int kDeg = 10;
static constexpr int kD   = 512;
static constexpr int kFF  = 2048;
static constexpr int kRows = 48;   // rows per MFMA block
static constexpr int kLdA  = 584;  // node_h LDS row stride (bf16 elems, +8 pad)
static constexpr int kLdG  = 520;  // gemm LDS row stride for 512-k chunk (+8 pad)

using short8  = __attribute__((ext_vector_type(8))) short;
using floatx4 = __attribute__((ext_vector_type(4))) float;

__device__ inline unsigned short f2bf(float f) {
    union { float f; unsigned u; } v; v.f = f;
    unsigned r = v.u + 0x7FFFu + ((v.u >> 16) & 1u);  // RNE
    return (unsigned short)(r >> 16);
}

// ---------------------------------------------------------------------------
// Pack node_h weights (ee_w || proj_w, K padded to 576) into b-frag order.
// ---------------------------------------------------------------------------
__global__ __launch_bounds__(256) void pack_node_w_kernel(
    const float* __restrict__ ee_w, const float* __restrict__ proj_w,
    ushort* __restrict__ Bp)
{
    int tid  = blockIdx.x * 256 + threadIdx.x;   // 0 .. 36863
    int lane = tid & 63;
    int tile = tid >> 6;                          // kc*32 + ct
    int n     = (tile & 31) * 16 + (lane & 15);
    int kbase = (tile >> 5) * 32 + (lane >> 4) * 8;
    ushort v[8];
    #pragma unroll
    for (int j = 0; j < 8; ++j) {
        int k = kbase + j;
        float f = 0.f;
        if (k < 256)      f = ee_w[(size_t)n * 256 + k];
        else if (k < 556) f = proj_w[(size_t)n * 300 + (k - 256)];
        v[j] = f2bf(f);
    }
    uint4 u;
    u.x = (unsigned)v[0] | ((unsigned)v[1] << 16);
    u.y = (unsigned)v[2] | ((unsigned)v[3] << 16);
    u.z = (unsigned)v[4] | ((unsigned)v[5] << 16);
    u.w = (unsigned)v[6] | ((unsigned)v[7] << 16);
    *(uint4*)(Bp + (size_t)tid * 8) = u;
}

// ---------------------------------------------------------------------------
// Pack the 12 (512x512) attention weight matrices into b-frag order.
// blockIdx.y = l*6 + {sa_v, sa_out, ca_q, ca_k, ca_v, ca_out}
// Layout per matrix: offset = ((kc*NT + ct)*64 + lane)*8, NT=32, kc<16.
// ---------------------------------------------------------------------------
__global__ __launch_bounds__(256) void pack512_many_kernel(
    const float* __restrict__ sa_in_w, const float* __restrict__ sa_out_w,
    const float* __restrict__ ca_in_w, const float* __restrict__ ca_out_w,
    ushort* __restrict__ dst)
{
    int y = blockIdx.y, l = y / 6, m = y % 6;
    const float* W;
    switch (m) {
        case 0: W = sa_in_w  + (size_t)l * 3 * kD * kD + (size_t)2 * kD * kD; break;
        case 1: W = sa_out_w + (size_t)l * kD * kD; break;
        case 2: W = ca_in_w  + (size_t)l * 3 * kD * kD; break;
        case 3: W = ca_in_w  + (size_t)l * 3 * kD * kD + (size_t)kD * kD; break;
        case 4: W = ca_in_w  + (size_t)l * 3 * kD * kD + (size_t)2 * kD * kD; break;
        default:W = ca_out_w + (size_t)l * kD * kD; break;
    }
    int tid  = blockIdx.x * 256 + threadIdx.x;   // 0..32767
    int lane = tid & 63;
    int tile = tid >> 6;                          // kc*32+ct
    int n  = (tile & 31) * 16 + (lane & 15);
    int kb = (tile >> 5) * 32 + (lane >> 4) * 8;
    const float* src = W + (size_t)n * 512 + kb;
    ushort v[8];
    #pragma unroll
    for (int j = 0; j < 8; ++j) v[j] = f2bf(src[j]);
    uint4 u;
    u.x = (unsigned)v[0] | ((unsigned)v[1] << 16);
    u.y = (unsigned)v[2] | ((unsigned)v[3] << 16);
    u.z = (unsigned)v[4] | ((unsigned)v[5] << 16);
    u.w = (unsigned)v[6] | ((unsigned)v[7] << 16);
    *(uint4*)(dst + (size_t)y * 262144 + (size_t)tid * 8) = u;
}

// Generic pack: W is (N x K) row-major; blockIdx.y selects matrix.
__global__ __launch_bounds__(256) void pack_generic_kernel(
    const float* __restrict__ src, size_t srcStride,
    ushort* __restrict__ dst, size_t dstStride, int N, int K)
{
    int tid  = blockIdx.x * 256 + threadIdx.x;
    int NT = N >> 4;
    int lane = tid & 63;
    int tile = tid >> 6;
    int ct = tile % NT, kc = tile / NT;
    int n  = ct * 16 + (lane & 15);
    int kb = kc * 32 + (lane >> 4) * 8;
    const float* W = src + blockIdx.y * srcStride + (size_t)n * K + kb;
    ushort v[8];
    #pragma unroll
    for (int j = 0; j < 8; ++j) v[j] = f2bf(W[j]);
    uint4 u;
    u.x = (unsigned)v[0] | ((unsigned)v[1] << 16);
    u.y = (unsigned)v[2] | ((unsigned)v[3] << 16);
    u.z = (unsigned)v[4] | ((unsigned)v[5] << 16);
    u.w = (unsigned)v[6] | ((unsigned)v[7] << 16);
    *(uint4*)(dst + blockIdx.y * dstStride + (size_t)tid * 8) = u;
}

// ---------------------------------------------------------------------------
// MFMA node_h (unchanged from R2).
// ---------------------------------------------------------------------------
__global__ __launch_bounds__(512, 2) void node_h_mfma(
    const int* __restrict__ nid,
    const float* __restrict__ content,
    const float* __restrict__ node_emb_w,
    const ushort* __restrict__ Bp,
    const float* __restrict__ ee_b, const float* __restrict__ proj_b,
    const float* __restrict__ proj_g, const float* __restrict__ proj_beta,
    float* __restrict__ hout, int ldh, int n)
{
    __shared__ __align__(16) ushort As[kRows * kLdA];
    __shared__ float redS[8][kRows], redQ[8][kRows];
    __shared__ float meanv[kRows], rstdv[kRows], rowinv[kRows];

    const int t    = threadIdx.x;
    const int lane = t & 63;
    const int wv   = t >> 6;
    const int quad = lane >> 4;
    const int l15  = lane & 15;
    const int row0 = blockIdx.x * kRows;

    for (int it = 0; it < 14; ++it) {
        int flat = it * 512 + t;
        if (flat < kRows * 144) {
            int r  = flat / 144;
            int k4 = flat - r * 144;
            int row = row0 + r; if (row >= n) row = n - 1;
            float4 f = make_float4(0.f, 0.f, 0.f, 0.f);
            if (k4 < 64)
                f = *(const float4*)(node_emb_w + ((size_t)(nid[row] + 1)) * 256 + k4 * 4);
            else if (k4 < 139)
                f = *(const float4*)(content + (size_t)row * 300 + (k4 - 64) * 4);
            ushort4 o = make_ushort4(f2bf(f.x), f2bf(f.y), f2bf(f.z), f2bf(f.w));
            *(ushort4*)(As + (size_t)r * kLdA + k4 * 4) = o;
        }
    }
    __syncthreads();

    floatx4 accN[3][4] = {};
    floatx4 accC[3][4] = {};
    const short8* BpV = (const short8*)Bp;

    #pragma unroll
    for (int kc = 0; kc < 8; ++kc) {
        const short8* bp = BpV + (size_t)(kc * 32 + wv * 4) * 64 + lane;
        short8 b0 = bp[0], b1 = bp[64], b2 = bp[128], b3 = bp[192];
        short8 a[3];
        #pragma unroll
        for (int rt = 0; rt < 3; ++rt)
            a[rt] = *(const short8*)(As + (size_t)(rt * 16 + l15) * kLdA + kc * 32 + quad * 8);
        #pragma unroll
        for (int rt = 0; rt < 3; ++rt) {
            accN[rt][0] = __builtin_amdgcn_mfma_f32_16x16x32_bf16(a[rt], b0, accN[rt][0], 0, 0, 0);
            accN[rt][1] = __builtin_amdgcn_mfma_f32_16x16x32_bf16(a[rt], b1, accN[rt][1], 0, 0, 0);
            accN[rt][2] = __builtin_amdgcn_mfma_f32_16x16x32_bf16(a[rt], b2, accN[rt][2], 0, 0, 0);
            accN[rt][3] = __builtin_amdgcn_mfma_f32_16x16x32_bf16(a[rt], b3, accN[rt][3], 0, 0, 0);
        }
    }
    #pragma unroll
    for (int kc = 8; kc < 18; ++kc) {
        const short8* bp = BpV + (size_t)(kc * 32 + wv * 4) * 64 + lane;
        short8 b0 = bp[0], b1 = bp[64], b2 = bp[128], b3 = bp[192];
        short8 a[3];
        #pragma unroll
        for (int rt = 0; rt < 3; ++rt)
            a[rt] = *(const short8*)(As + (size_t)(rt * 16 + l15) * kLdA + kc * 32 + quad * 8);
        #pragma unroll
        for (int rt = 0; rt < 3; ++rt) {
            accC[rt][0] = __builtin_amdgcn_mfma_f32_16x16x32_bf16(a[rt], b0, accC[rt][0], 0, 0, 0);
            accC[rt][1] = __builtin_amdgcn_mfma_f32_16x16x32_bf16(a[rt], b1, accC[rt][1], 0, 0, 0);
            accC[rt][2] = __builtin_amdgcn_mfma_f32_16x16x32_bf16(a[rt], b2, accC[rt][2], 0, 0, 0);
            accC[rt][3] = __builtin_amdgcn_mfma_f32_16x16x32_bf16(a[rt], b3, accC[rt][3], 0, 0, 0);
        }
    }

    const int colbase = wv * 64 + l15;
    float pb[4], pg[4], pbt[4], eb[4];
    #pragma unroll
    for (int ct = 0; ct < 4; ++ct) {
        int c = colbase + ct * 16;
        pb[ct]  = proj_b[c];
        pg[ct]  = proj_g[c];
        pbt[ct] = proj_beta[c];
        eb[ct]  = ee_b[c];
    }

    float s12[12], q12[12];
    #pragma unroll
    for (int rt = 0; rt < 3; ++rt) {
        #pragma unroll
        for (int i = 0; i < 4; ++i) {
            float s = 0.f, q = 0.f;
            #pragma unroll
            for (int ct = 0; ct < 4; ++ct) {
                float c = accC[rt][ct][i] + pb[ct];
                c = (c >= 0.f) ? c : 0.1f * c;
                accC[rt][ct][i] = c;
                s += c; q = fmaf(c, c, q);
            }
            s12[rt * 4 + i] = s; q12[rt * 4 + i] = q;
        }
    }
    #pragma unroll
    for (int idx = 0; idx < 12; ++idx) {
        #pragma unroll
        for (int m = 1; m < 16; m <<= 1) {
            s12[idx] += __shfl_xor(s12[idx], m);
            q12[idx] += __shfl_xor(q12[idx], m);
        }
    }
    if (l15 == 0) {
        #pragma unroll
        for (int rt = 0; rt < 3; ++rt)
            #pragma unroll
            for (int i = 0; i < 4; ++i) {
                int rl = rt * 16 + quad * 4 + i;
                redS[wv][rl] = s12[rt * 4 + i];
                redQ[wv][rl] = q12[rt * 4 + i];
            }
    }
    __syncthreads();
    if (t < kRows) {
        float s = 0.f, q = 0.f;
        #pragma unroll
        for (int w = 0; w < 8; ++w) { s += redS[w][t]; q += redQ[w][t]; }
        float m   = s * (1.f / 512.f);
        float var = q * (1.f / 512.f) - m * m;
        meanv[t] = m;
        rstdv[t] = rsqrtf(var + 1e-5f);
    }
    __syncthreads();

    #pragma unroll
    for (int rt = 0; rt < 3; ++rt) {
        #pragma unroll
        for (int i = 0; i < 4; ++i) {
            int rl = rt * 16 + quad * 4 + i;
            float m = meanv[rl], rs = rstdv[rl];
            float psq = 0.f;
            #pragma unroll
            for (int ct = 0; ct < 4; ++ct) {
                float cn = (accC[rt][ct][i] - m) * rs * pg[ct] + pbt[ct];
                float h  = accN[rt][ct][i] + eb[ct] + cn;
                accN[rt][ct][i] = h;
                psq = fmaf(h, h, psq);
            }
            q12[rt * 4 + i] = psq;
        }
    }
    #pragma unroll
    for (int idx = 0; idx < 12; ++idx)
        #pragma unroll
        for (int m = 1; m < 16; m <<= 1)
            q12[idx] += __shfl_xor(q12[idx], m);
    if (l15 == 0) {
        #pragma unroll
        for (int rt = 0; rt < 3; ++rt)
            #pragma unroll
            for (int i = 0; i < 4; ++i)
                redS[wv][rt * 16 + quad * 4 + i] = q12[rt * 4 + i];
    }
    __syncthreads();
    if (t < kRows) {
        float s = 0.f;
        #pragma unroll
        for (int w = 0; w < 8; ++w) s += redS[w][t];
        rowinv[t] = 1.f / fmaxf(sqrtf(s), 1e-5f);
    }
    __syncthreads();

    #pragma unroll
    for (int rt = 0; rt < 3; ++rt) {
        #pragma unroll
        for (int i = 0; i < 4; ++i) {
            int rl = rt * 16 + quad * 4 + i;
            int grow = row0 + rl;
            if (grow < n) {
                float inv = rowinv[rl];
                float* dst = hout + (size_t)grow * ldh + colbase;
                #pragma unroll
                for (int ct = 0; ct < 4; ++ct)
                    dst[ct * 16] = accN[rt][ct][i] * inv;
            }
        }
    }
}

// ---------------------------------------------------------------------------
// MFMA GEMM: C[:, nb*512..+512] = A(MxK) @ W^T + bias, fused epilogue.
// 48 rows x 512 cols per block, 512 threads (8 waves), K staged in 512 chunks.
// EPI: 0=plain  1=gelu(exact)  2=residual+LayerNorm (N==512, nb==0)
// ---------------------------------------------------------------------------
__device__ inline float gelu_exact(float x) {
    return 0.5f * x * (1.f + erff(x * 0.70710678118654752f));
}

template<int EPI>
__global__ __launch_bounds__(512, 2) void gemm_mfma(
    const float* __restrict__ A, int lda,
    const ushort* __restrict__ Bp, const float* __restrict__ bias,
    float* __restrict__ C, int ldc,
    const float* __restrict__ resid,
    const float* __restrict__ lng, const float* __restrict__ lnb,
    int M, int K, int N)
{
    __shared__ __align__(16) ushort As[kRows * kLdG];      // 49920 B
    __shared__ float redS[8][kRows], redQ[8][kRows];
    __shared__ float meanv[kRows], rstdv[kRows];

    const int t    = threadIdx.x;
    const int lane = t & 63;
    const int wv   = t >> 6;
    const int quad = lane >> 4;
    const int l15  = lane & 15;
    const int row0 = blockIdx.x * kRows;
    const int nb   = blockIdx.y;
    const int NT   = N >> 4;

    floatx4 acc[3][4] = {};
    const short8* BpV = (const short8*)Bp;

    for (int k0 = 0; k0 < K; k0 += 512) {
        // stage A chunk (48 x 512) fp32 -> bf16
        #pragma unroll
        for (int it = 0; it < 12; ++it) {
            int flat = it * 512 + t;        // 6144 float4 slots
            int r  = flat >> 7;
            int k4 = flat & 127;
            int row = row0 + r; if (row >= M) row = M - 1;
            float4 f = *(const float4*)(A + (size_t)row * lda + k0 + k4 * 4);
            ushort4 o = make_ushort4(f2bf(f.x), f2bf(f.y), f2bf(f.z), f2bf(f.w));
            *(ushort4*)(As + (size_t)r * kLdG + k4 * 4) = o;
        }
        __syncthreads();
        const int g0 = k0 >> 5;
        #pragma unroll
        for (int kc = 0; kc < 16; ++kc) {
            const short8* bp = BpV + ((size_t)(g0 + kc) * NT + nb * 32 + wv * 4) * 64 + lane;
            short8 b0 = bp[0], b1 = bp[64], b2 = bp[128], b3 = bp[192];
            short8 a[3];
            #pragma unroll
            for (int rt = 0; rt < 3; ++rt)
                a[rt] = *(const short8*)(As + (size_t)(rt * 16 + l15) * kLdG + kc * 32 + quad * 8);
            #pragma unroll
            for (int rt = 0; rt < 3; ++rt) {
                acc[rt][0] = __builtin_amdgcn_mfma_f32_16x16x32_bf16(a[rt], b0, acc[rt][0], 0, 0, 0);
                acc[rt][1] = __builtin_amdgcn_mfma_f32_16x16x32_bf16(a[rt], b1, acc[rt][1], 0, 0, 0);
                acc[rt][2] = __builtin_amdgcn_mfma_f32_16x16x32_bf16(a[rt], b2, acc[rt][2], 0, 0, 0);
                acc[rt][3] = __builtin_amdgcn_mfma_f32_16x16x32_bf16(a[rt], b3, acc[rt][3], 0, 0, 0);
            }
        }
        __syncthreads();
    }

    const int colloc = wv * 64 + l15;           // 0..511 within col-block
    float b[4];
    #pragma unroll
    for (int ct = 0; ct < 4; ++ct) b[ct] = bias[nb * 512 + colloc + ct * 16];

    if constexpr (EPI == 0 || EPI == 1) {
        #pragma unroll
        for (int rt = 0; rt < 3; ++rt) {
            #pragma unroll
            for (int i = 0; i < 4; ++i) {
                int row = row0 + rt * 16 + quad * 4 + i;
                if (row < M) {
                    float* dst = C + (size_t)row * ldc + nb * 512 + colloc;
                    #pragma unroll
                    for (int ct = 0; ct < 4; ++ct) {
                        float v = acc[rt][ct][i] + b[ct];
                        if (EPI == 1) v = gelu_exact(v);
                        dst[ct * 16] = v;
                    }
                }
            }
        }
    } else {
        float lg[4], lb[4];
        #pragma unroll
        for (int ct = 0; ct < 4; ++ct) {
            lg[ct] = lng[colloc + ct * 16];
            lb[ct] = lnb[colloc + ct * 16];
        }
        float s12[12], q12[12];
        #pragma unroll
        for (int rt = 0; rt < 3; ++rt) {
            #pragma unroll
            for (int i = 0; i < 4; ++i) {
                int rl = rt * 16 + quad * 4 + i;
                int row = row0 + rl; if (row >= M) row = M - 1;
                const float* rr = resid + (size_t)row * 512 + colloc;
                float s = 0.f, q = 0.f;
                #pragma unroll
                for (int ct = 0; ct < 4; ++ct) {
                    float h = acc[rt][ct][i] + b[ct] + rr[ct * 16];
                    acc[rt][ct][i] = h;
                    s += h; q = fmaf(h, h, q);
                }
                s12[rt * 4 + i] = s; q12[rt * 4 + i] = q;
            }
        }
        #pragma unroll
        for (int idx = 0; idx < 12; ++idx) {
            #pragma unroll
            for (int m = 1; m < 16; m <<= 1) {
                s12[idx] += __shfl_xor(s12[idx], m);
                q12[idx] += __shfl_xor(q12[idx], m);
            }
        }
        if (l15 == 0) {
            #pragma unroll
            for (int rt = 0; rt < 3; ++rt)
                #pragma unroll
                for (int i = 0; i < 4; ++i) {
                    int rl = rt * 16 + quad * 4 + i;
                    redS[wv][rl] = s12[rt * 4 + i];
                    redQ[wv][rl] = q12[rt * 4 + i];
                }
        }
        __syncthreads();
        if (t < kRows) {
            float s = 0.f, q = 0.f;
            #pragma unroll
            for (int w = 0; w < 8; ++w) { s += redS[w][t]; q += redQ[w][t]; }
            float m   = s * (1.f / 512.f);
            float var = q * (1.f / 512.f) - m * m;
            meanv[t] = m;
            rstdv[t] = rsqrtf(var + 1e-5f);
        }
        __syncthreads();
        #pragma unroll
        for (int rt = 0; rt < 3; ++rt) {
            #pragma unroll
            for (int i = 0; i < 4; ++i) {
                int rl = rt * 16 + quad * 4 + i;
                int row = row0 + rl;
                if (row < M) {
                    float m = meanv[rl], rs = rstdv[rl];
                    float* dst = C + (size_t)row * 512 + colloc;
                    #pragma unroll
                    for (int ct = 0; ct < 4; ++ct)
                        dst[ct * 16] = (acc[rt][ct][i] - m) * rs * lg[ct] + lb[ct];
                }
            }
        }
    }
}

// ---------------------------------------------------------------------------
__device__ inline float block_sum256(float v, float* red4) {
    #pragma unroll
    for (int off = 32; off > 0; off >>= 1) v += __shfl_down(v, off);
    if ((threadIdx.x & 63) == 0) red4[threadIdx.x >> 6] = v;
    __syncthreads();
    return red4[0] + red4[1] + red4[2] + red4[3];
}

__global__ __launch_bounds__(256) void agg_norm1_kernel(
    const float* __restrict__ h0, const int* __restrict__ esrc,
    float* __restrict__ h1cat)
{
    __shared__ int idx[kDeg];
    __shared__ float red4[4];
    int i = blockIdx.x, t = threadIdx.x;
    if (t < kDeg) idx[t] = esrc[i * kDeg + t];
    __syncthreads();
    float s0 = 0.f, s1 = 0.f;
    for (int e = 0; e < kDeg; ++e) {
        const float* hr = h0 + (size_t)idx[e] * 512;
        s0 += hr[t]; s1 += hr[t + 256];
    }
    s0 *= 0.1f; s1 *= 0.1f;
    size_t base = (size_t)i * 1024;
    float o0 = h1cat[base + 512 + t];
    float o1 = h1cat[base + 768 + t];
    float tot = block_sum256(s0 * s0 + s1 * s1 + o0 * o0 + o1 * o1, red4);
    float inv = 1.f / fmaxf(sqrtf(tot), 1e-5f);
    h1cat[base + t]       = s0 * inv;
    h1cat[base + 256 + t] = s1 * inv;
    h1cat[base + 512 + t] = o0 * inv;
    h1cat[base + 768 + t] = o1 * inv;
}

__global__ __launch_bounds__(256) void agg2_kernel(
    const float* __restrict__ h1cat, const int* __restrict__ esrc,
    float* __restrict__ m2)
{
    __shared__ int idx[kDeg];
    int i = blockIdx.x, t = threadIdx.x;
    if (t < kDeg) idx[t] = esrc[i * kDeg + t];
    __syncthreads();
    float s0 = 0.f, s1 = 0.f, s2 = 0.f, s3 = 0.f;
    for (int e = 0; e < kDeg; ++e) {
        const float* hr = h1cat + (size_t)idx[e] * 1024;
        s0 += hr[t]; s1 += hr[t + 256]; s2 += hr[t + 512]; s3 += hr[t + 768];
    }
    size_t base = (size_t)i * 1024;
    m2[base + t]       = s0 * 0.1f;
    m2[base + 256 + t] = s1 * 0.1f;
    m2[base + 512 + t] = s2 * 0.1f;
    m2[base + 768 + t] = s3 * 0.1f;
}

// Kb/Vb rows: 2i = memory slot 0, 2i+1 = slot 1 (m2 viewed as (2*N2, 512)).
__global__ __launch_bounds__(256) void attn_combine_kernel(
    const float* __restrict__ Q,
    const float* __restrict__ Kb, const float* __restrict__ Vb,
    float* __restrict__ O)
{
    __shared__ float red[4][4];
    __shared__ float a[4];
    int i = blockIdx.x, t = threadIdx.x;
    size_t base  = (size_t)i * 512;
    size_t base0 = (size_t)(2 * i) * 512;
    size_t base1 = base0 + 512;
    float q0 = Q[base + t], q1 = Q[base + t + 256];
    float p00 = q0 * Kb[base0 + t];
    float p01 = q0 * Kb[base1 + t];
    float p10 = q1 * Kb[base0 + t + 256];
    float p11 = q1 * Kb[base1 + t + 256];
    #pragma unroll
    for (int off = 32; off > 0; off >>= 1) {
        p00 += __shfl_down(p00, off);
        p01 += __shfl_down(p01, off);
        p10 += __shfl_down(p10, off);
        p11 += __shfl_down(p11, off);
    }
    int w = t >> 6;
    if ((t & 63) == 0) { red[w][0] = p00; red[w][1] = p01; red[w][2] = p10; red[w][3] = p11; }
    __syncthreads();
    if (t == 0) {
        float s00 = (red[0][0] + red[1][0] + red[2][0] + red[3][0]) * 0.0625f;
        float s01 = (red[0][1] + red[1][1] + red[2][1] + red[3][1]) * 0.0625f;
        float s10 = (red[0][2] + red[1][2] + red[2][2] + red[3][2]) * 0.0625f;
        float s11 = (red[0][3] + red[1][3] + red[2][3] + red[3][3]) * 0.0625f;
        float m0 = fmaxf(s00, s01);
        float e0 = expf(s00 - m0), e1 = expf(s01 - m0);
        float d0 = e0 + e1;
        a[0] = e0 / d0; a[1] = e1 / d0;
        float m1 = fmaxf(s10, s11);
        float f0 = expf(s10 - m1), f1 = expf(s11 - m1);
        float d1 = f0 + f1;
        a[2] = f0 / d1; a[3] = f1 / d1;
    }
    __syncthreads();
    O[base + t]       = a[0] * Vb[base0 + t]       + a[1] * Vb[base1 + t];
    O[base + t + 256] = a[2] * Vb[base0 + t + 256] + a[3] * Vb[base1 + t + 256];
}

__global__ __launch_bounds__(256) void final_norm_kernel(
    const float* __restrict__ tgt, float* __restrict__ out)
{
    __shared__ float red4[4];
    int i = blockIdx.x, t = threadIdx.x;
    size_t base = (size_t)i * 512;
    float v0 = tgt[base + t], v1 = tgt[base + t + 256];
    float tot = block_sum256(v0 * v0 + v1 * v1, red4);
    float inv = 1.f / fmaxf(sqrtf(tot), 1e-5f);
    out[base + t]       = v0 * inv;
    out[base + t + 256] = v1 * inv;
}

// ---------------------------------------------------------------------------
extern "C" void kernel_launch(void* const* d_in, const int* in_sizes, int n_in,
                              void* d_out, int out_size, void* d_ws, size_t ws_size,
                              hipStream_t stream)
{
    (void)in_sizes; (void)n_in; (void)out_size; (void)ws_size;
    const int*   nid0       = (const int*)d_in[0];
    const int*   nid1       = (const int*)d_in[1];
    const int*   nid2       = (const int*)d_in[2];
    const int*   esrc0      = (const int*)d_in[3];
    const int*   esrc1      = (const int*)d_in[5];
    const float* content0   = (const float*)d_in[7];
    const float* content1   = (const float*)d_in[8];
    const float* content2   = (const float*)d_in[9];
    const float* node_emb_w = (const float*)d_in[10];
    const float* ee_w       = (const float*)d_in[11];
    const float* ee_b       = (const float*)d_in[12];
    const float* proj_w     = (const float*)d_in[13];
    const float* proj_b     = (const float*)d_in[14];
    const float* proj_g     = (const float*)d_in[15];
    const float* proj_beta  = (const float*)d_in[16];
    const float* sa_in_w    = (const float*)d_in[17];
    const float* sa_in_b    = (const float*)d_in[18];
    const float* sa_out_w   = (const float*)d_in[19];
    const float* sa_out_b   = (const float*)d_in[20];
    const float* ca_in_w    = (const float*)d_in[21];
    const float* ca_in_b    = (const float*)d_in[22];
    const float* ca_out_w   = (const float*)d_in[23];
    const float* ca_out_b   = (const float*)d_in[24];
    const float* lin1_w     = (const float*)d_in[25];
    const float* lin1_b     = (const float*)d_in[26];
    const float* lin2_w     = (const float*)d_in[27];
    const float* lin2_b     = (const float*)d_in[28];
    const float* n1_g       = (const float*)d_in[29];
    const float* n1_b       = (const float*)d_in[30];
    const float* n2_g       = (const float*)d_in[31];
    const float* n2_b       = (const float*)d_in[32];
    const float* n3_g       = (const float*)d_in[33];
    const float* n3_b       = (const float*)d_in[34];

    float* ws = (float*)d_ws;
    size_t off = 0;
    float* h0    = ws + off; off += (size_t)kN0 * 512;
    float* h1cat = ws + off; off += (size_t)kN1 * 1024;
    float* m2    = ws + off; off += (size_t)kN2 * 1024;
    float* tgt   = ws + off; off += (size_t)kN2 * 512;
    float* Qb    = ws + off; off += (size_t)kN2 * 512;
    float* Kb    = ws + off; off += (size_t)2 * kN2 * 512;
    float* Vb    = ws + off; off += (size_t)2 * kN2 * 512;
    float* Ob    = ws + off; off += (size_t)kN2 * 512;
    float* ffh   = ws + off; off += (size_t)kN2 * 2048;
    ushort* BpNode = (ushort*)(ws + off); off += 147456;           // 576*64*8 bf16
    ushort* Pw512  = (ushort*)(ws + off); off += 12 * 262144 / 2;  // 12 x 512x512
    ushort* Pl1    = (ushort*)(ws + off); off += 2 * 1048576 / 2;  // 2 x 2048x512
    ushort* Pl2    = (ushort*)(ws + off); off += 2 * 1048576 / 2;  // 2 x 512x2048

    dim3 blk(256);

    // ---- weight packing (4 launches) ----
    pack_node_w_kernel<<<dim3(144), blk, 0, stream>>>(ee_w, proj_w, BpNode);
    pack512_many_kernel<<<dim3(128, 12), blk, 0, stream>>>(
        sa_in_w, sa_out_w, ca_in_w, ca_out_w, Pw512);
    pack_generic_kernel<<<dim3(512, 2), blk, 0, stream>>>(
        lin1_w, (size_t)kFF * kD, Pl1, 1048576, kFF, kD);
    pack_generic_kernel<<<dim3(512, 2), blk, 0, stream>>>(
        lin2_w, (size_t)kD * kFF, Pl2, 1048576, kD, kFF);

    // ---- node_h ----
    node_h_mfma<<<dim3((kN0 + kRows - 1) / kRows), dim3(512), 0, stream>>>(
        nid0, content0, node_emb_w, BpNode, ee_b, proj_b, proj_g, proj_beta,
        h0, 512, kN0);
    node_h_mfma<<<dim3((kN1 + kRows - 1) / kRows), dim3(512), 0, stream>>>(
        nid1, content1, node_emb_w, BpNode, ee_b, proj_b, proj_g, proj_beta,
        h1cat + 512, 1024, kN1);
    node_h_mfma<<<dim3((kN2 + kRows - 1) / kRows), dim3(512), 0, stream>>>(
        nid2, content2, node_emb_w, BpNode, ee_b, proj_b, proj_g, proj_beta,
        tgt, 512, kN2);

    agg_norm1_kernel<<<dim3(kN1), blk, 0, stream>>>(h0, esrc0, h1cat);
    agg2_kernel<<<dim3(kN2), blk, 0, stream>>>(h1cat, esrc1, m2);

    const int M   = kN2;
    const int gM  = (M + kRows - 1) / kRows;       // 84
    const int gM2 = (2 * M + kRows - 1) / kRows;   // 167
    dim3 blk512(512);
    for (int l = 0; l < 2; ++l) {
        const ushort* sa_v_p   = Pw512 + (size_t)(l * 6 + 0) * 262144;
        const ushort* sa_out_p = Pw512 + (size_t)(l * 6 + 1) * 262144;
        const ushort* ca_q_p   = Pw512 + (size_t)(l * 6 + 2) * 262144;
        const ushort* ca_k_p   = Pw512 + (size_t)(l * 6 + 3) * 262144;
        const ushort* ca_v_p   = Pw512 + (size_t)(l * 6 + 4) * 262144;
        const ushort* ca_out_p = Pw512 + (size_t)(l * 6 + 5) * 262144;
        const ushort* l1_p     = Pl1 + (size_t)l * 1048576;
        const ushort* l2_p     = Pl2 + (size_t)l * 1048576;
        const float* sa_b = sa_in_b + (size_t)l * 3 * kD;
        const float* saob = sa_out_b + (size_t)l * kD;
        const float* ca_b = ca_in_b + (size_t)l * 3 * kD;
        const float* caob = ca_out_b + (size_t)l * kD;
        const float* l1b = lin1_b + (size_t)l * kFF;
        const float* l2b = lin2_b + (size_t)l * kD;

        // self-attention (seq len 1 => o = v-projection)
        gemm_mfma<0><<<dim3(gM, 1), blk512, 0, stream>>>(
            tgt, 512, sa_v_p, sa_b + 2 * kD, Qb, 512,
            nullptr, nullptr, nullptr, M, 512, 512);
        gemm_mfma<2><<<dim3(gM, 1), blk512, 0, stream>>>(
            Qb, 512, sa_out_p, saob, tgt, 512,
            tgt, n1_g + l * kD, n1_b + l * kD, M, 512, 512);

        // cross-attention
        gemm_mfma<0><<<dim3(gM, 1), blk512, 0, stream>>>(
            tgt, 512, ca_q_p, ca_b, Qb, 512,
            nullptr, nullptr, nullptr, M, 512, 512);
        gemm_mfma<0><<<dim3(gM2, 1), blk512, 0, stream>>>(
            m2, 512, ca_k_p, ca_b + kD, Kb, 512,
            nullptr, nullptr, nullptr, 2 * M, 512, 512);
        gemm_mfma<0><<<dim3(gM2, 1), blk512, 0, stream>>>(
            m2, 512, ca_v_p, ca_b + 2 * kD, Vb, 512,
            nullptr, nullptr, nullptr, 2 * M, 512, 512);
        attn_combine_kernel<<<dim3(M), blk, 0, stream>>>(Qb, Kb, Vb, Ob);
        gemm_mfma<2><<<dim3(gM, 1), blk512, 0, stream>>>(
            Ob, 512, ca_out_p, caob, tgt, 512,
            tgt, n2_g + l * kD, n2_b + l * kD, M, 512, 512);

        // feed-forward
        gemm_mfma<1><<<dim3(gM, 4), blk512, 0, stream>>>(
            tgt, 512, l1_p, l1b, ffh, 2048,
            nullptr, nullptr, nullptr, M, 512, 2048);
        gemm_mfma<2><<<dim3(gM, 1), blk512, 0, stream>>>(
            ffh, 2048, l2_p, l2b, tgt, 512,
            tgt, n3_g + l * kD, n3_b + l * kD, M, 2048, 512);
    }

    final_norm_kernel<<<dim3(kN2), blk, 0, stream>>>(tgt, (float*)d_out);
}